// Round 2
// baseline (715.643 us; speedup 1.0000x reference)
//
#include <hip/hip_runtime.h>

// Problem constants (from reference): B=16, CIN=128, COUT=3, WDIM=512, H=W=256
#define B_    16
#define CIN_  128
#define COUT_ 3
#define WDIM_ 512
#define HW_   65536   // 256*256

#define TILE_PX  4096   // pixels per block-tile per plane (16 KiB)
#define SWEEP_PX 1024   // pixels per 256-thread sweep (4 KiB)

typedef float fvec4 __attribute__((ext_vector_type(4)));

// ---------------------------------------------------------------------------
// Kernel 1: coeff[b][i] = (w[b,:]·affine_w[i,:] + affine_b[i]) * weight[o,i]
// for o=0..2, packed as fvec4 (w component unused). 16 blocks x 128 threads.
// ---------------------------------------------------------------------------
__global__ __launch_bounds__(128) void style_coeff_kernel(
    const float* __restrict__ w,         // (B, WDIM)
    const float* __restrict__ weight,    // (COUT, CIN)
    const float* __restrict__ affine_w,  // (CIN, WDIM)
    const float* __restrict__ affine_b,  // (CIN,)
    fvec4* __restrict__ coeff)           // (B, CIN) fvec4
{
    const int b = blockIdx.x;
    const int c = threadIdx.x;  // channel 0..127

    const fvec4* wb = (const fvec4*)(w + (size_t)b * WDIM_);
    const fvec4* aw = (const fvec4*)(affine_w + (size_t)c * WDIM_);

    float s = 0.0f;
#pragma unroll 8
    for (int d = 0; d < WDIM_ / 4; ++d) {
        fvec4 a = aw[d];
        fvec4 v = wb[d];
        s += a.x * v.x + a.y * v.y + a.z * v.z + a.w * v.w;
    }
    s += affine_b[c];

    fvec4 o;
    o.x = s * weight[0 * CIN_ + c];
    o.y = s * weight[1 * CIN_ + c];
    o.z = s * weight[2 * CIN_ + c];
    o.w = 0.0f;
    coeff[(size_t)b * CIN_ + c] = o;
}

// ---------------------------------------------------------------------------
// Kernel 2: out[b,o,p] = sum_i x[b,i,p] * coeff[b][i][o] + bias[o]
//
// RESTRUCTURE vs previous round (address-stream locality fix):
// Old: 1024 blocks, 4 KiB per plane per block; a wave's 16 in-flight loads
//      differed ONLY in bits >=18 (256 KiB plane stride) -> channel camping
//      + zero DRAM row locality -> 1.6 TB/s (26% of achievable).
// New: 256 blocks (1/CU), 16 KiB tile per plane (4 sweeps x 4 KiB),
//      channel loop unrolled x4. A wave's 16 in-flight loads span
//      4 planes x 4 segments (bits 12-13 vary), and each block streams
//      16 KiB contiguous per plane in one burst.
// ---------------------------------------------------------------------------
__global__ __launch_bounds__(256) void torgb_kernel(
    const float*  __restrict__ x,      // (B, CIN, HW)
    const fvec4*  __restrict__ coeff,  // (B, CIN)
    const float*  __restrict__ bias,   // (COUT,)
    float*        __restrict__ out)    // (B, COUT, HW)
{
    __shared__ fvec4 sc[CIN_];

    const int b = blockIdx.y;
    const int t = threadIdx.x;

    if (t < CIN_) sc[t] = coeff[(size_t)b * CIN_ + t];
    __syncthreads();

    // base pixel of this thread's first fvec4 within the block tile
    const size_t p0 = (size_t)blockIdx.x * TILE_PX + (size_t)t * 4;
    const float* xb = x + (size_t)b * CIN_ * HW_ + p0;

    // acc[k][o]: sweep k (k*4KiB apart), output channel o
    fvec4 acc[4][3];
#pragma unroll
    for (int k = 0; k < 4; ++k)
#pragma unroll
        for (int o = 0; o < 3; ++o)
            acc[k][o] = (fvec4){0.f, 0.f, 0.f, 0.f};

    for (int i = 0; i < CIN_; i += 4) {
        // 16 independent loads: 4 planes x 4 sweeps, issued together
        fvec4 xv[4][4];  // [di][k]
#pragma unroll
        for (int di = 0; di < 4; ++di)
#pragma unroll
            for (int k = 0; k < 4; ++k)
                xv[di][k] = *(const fvec4*)(xb + (size_t)(i + di) * HW_
                                               + (size_t)k * SWEEP_PX);

#pragma unroll
        for (int di = 0; di < 4; ++di) {
            const fvec4 c = sc[i + di];
#pragma unroll
            for (int k = 0; k < 4; ++k) {
                acc[k][0] += xv[di][k] * c.x;
                acc[k][1] += xv[di][k] * c.y;
                acc[k][2] += xv[di][k] * c.z;
            }
        }
    }

    const float b0 = bias[0], b1 = bias[1], b2 = bias[2];
    float* ob = out + (size_t)b * COUT_ * HW_ + p0;

#pragma unroll
    for (int k = 0; k < 4; ++k) {
        fvec4 r0 = acc[k][0] + b0;
        fvec4 r1 = acc[k][1] + b1;
        fvec4 r2 = acc[k][2] + b2;
        __builtin_nontemporal_store(r0, (fvec4*)(ob + 0 * (size_t)HW_ + (size_t)k * SWEEP_PX));
        __builtin_nontemporal_store(r1, (fvec4*)(ob + 1 * (size_t)HW_ + (size_t)k * SWEEP_PX));
        __builtin_nontemporal_store(r2, (fvec4*)(ob + 2 * (size_t)HW_ + (size_t)k * SWEEP_PX));
    }
}

extern "C" void kernel_launch(void* const* d_in, const int* in_sizes, int n_in,
                              void* d_out, int out_size, void* d_ws, size_t ws_size,
                              hipStream_t stream) {
    const float* x        = (const float*)d_in[0];  // (16,128,256,256)
    const float* w        = (const float*)d_in[1];  // (16,512)
    const float* weight   = (const float*)d_in[2];  // (3,128,1,1)
    const float* bias     = (const float*)d_in[3];  // (3,)
    const float* affine_w = (const float*)d_in[4];  // (128,512)
    const float* affine_b = (const float*)d_in[5];  // (128,)
    float* out = (float*)d_out;                     // (16,3,256,256)

    fvec4* coeff = (fvec4*)d_ws;                    // 16*128*16 B = 32 KB

    style_coeff_kernel<<<dim3(B_), dim3(CIN_), 0, stream>>>(
        w, weight, affine_w, affine_b, coeff);

    dim3 grid(HW_ / TILE_PX, B_);  // (16, 16) = 256 blocks, 1 per CU
    torgb_kernel<<<grid, dim3(256), 0, stream>>>(x, coeff, bias, out);
}

// Round 4
// 669.563 us; speedup vs baseline: 1.0688x; 1.0688x over previous
//
#include <hip/hip_runtime.h>

// Problem constants (from reference): B=16, CIN=128, COUT=3, WDIM=512, H=W=256
#define B_    16
#define CIN_  128
#define COUT_ 3
#define WDIM_ 512
#define HW_   65536   // 256*256

typedef float fvec4 __attribute__((ext_vector_type(4)));
typedef float fvec2 __attribute__((ext_vector_type(2)));

// ---------------------------------------------------------------------------
// Kernel 1: coeff[b][i] = (w[b,:]·affine_w[i,:] + affine_b[i]) * weight[o,i]
// for o=0..2, packed as fvec4 (w component unused). 16 blocks x 128 threads.
// ---------------------------------------------------------------------------
__global__ __launch_bounds__(128) void style_coeff_kernel(
    const float* __restrict__ w,         // (B, WDIM)
    const float* __restrict__ weight,    // (COUT, CIN)
    const float* __restrict__ affine_w,  // (CIN, WDIM)
    const float* __restrict__ affine_b,  // (CIN,)
    fvec4* __restrict__ coeff)           // (B, CIN) fvec4
{
    const int b = blockIdx.x;
    const int c = threadIdx.x;  // channel 0..127

    const fvec4* wb = (const fvec4*)(w + (size_t)b * WDIM_);
    const fvec4* aw = (const fvec4*)(affine_w + (size_t)c * WDIM_);

    float s = 0.0f;
#pragma unroll 8
    for (int d = 0; d < WDIM_ / 4; ++d) {
        fvec4 a = aw[d];
        fvec4 v = wb[d];
        s += a.x * v.x + a.y * v.y + a.z * v.z + a.w * v.w;
    }
    s += affine_b[c];

    fvec4 o;
    o.x = s * weight[0 * CIN_ + c];
    o.y = s * weight[1 * CIN_ + c];
    o.z = s * weight[2 * CIN_ + c];
    o.w = 0.0f;
    coeff[(size_t)b * CIN_ + c] = o;
}

// ---------------------------------------------------------------------------
// Kernel 2: out[b,o,p] = sum_i x[b,i,p] * coeff[b][i][o] + bias[o]
//
// OCCUPANCY EXPERIMENT (resubmit — round 3 was an infra failure, no data):
//   R0/R1: 16 waves/CU, fvec4/thread  -> ~1.6 TB/s read
//   R2:     4 waves/CU, 16 loads in flight -> slightly worse
// Theory: per-wave effective outstanding-read capacity is small; read BW
// scales with RESIDENT WAVES, not issued loads per wave.
// So: fvec2 per thread (2 KiB chunk/block-plane), grid (128,16)=2048 blocks
// = 8 blocks/CU = 32 waves/CU (hardware max), __launch_bounds__(256,8)
// (VGPR cap 64; loop uses ~50, no spill). NT loads (R0 config, best).
// ---------------------------------------------------------------------------
__global__ __launch_bounds__(256, 8) void torgb_kernel(
    const float*  __restrict__ x,      // (B, CIN, HW)
    const fvec4*  __restrict__ coeff,  // (B, CIN)
    const float*  __restrict__ bias,   // (COUT,)
    float*        __restrict__ out)    // (B, COUT, HW)
{
    __shared__ fvec4 sc[CIN_];

    const int b = blockIdx.y;
    const int t = threadIdx.x;

    if (t < CIN_) sc[t] = coeff[(size_t)b * CIN_ + t];
    __syncthreads();

    // 2-pixel group: block covers 512 px per plane, 128 chunks per plane
    const size_t p2 = ((size_t)blockIdx.x * 256 + t) * 2;
    const float* xb = x + (size_t)b * CIN_ * HW_ + p2;

    fvec2 a0 = {0.f, 0.f};
    fvec2 a1 = {0.f, 0.f};
    fvec2 a2 = {0.f, 0.f};

#pragma unroll 16
    for (int i = 0; i < CIN_; ++i) {
        fvec2 xv = __builtin_nontemporal_load((const fvec2*)(xb + (size_t)i * HW_));
        fvec4 c  = sc[i];
        a0.x = fmaf(xv.x, c.x, a0.x);
        a0.y = fmaf(xv.y, c.x, a0.y);
        a1.x = fmaf(xv.x, c.y, a1.x);
        a1.y = fmaf(xv.y, c.y, a1.y);
        a2.x = fmaf(xv.x, c.z, a2.x);
        a2.y = fmaf(xv.y, c.z, a2.y);
    }

    const float b0 = bias[0], b1 = bias[1], b2 = bias[2];
    float* ob = out + (size_t)b * COUT_ * HW_ + p2;

    fvec2 r0 = {a0.x + b0, a0.y + b0};
    fvec2 r1 = {a1.x + b1, a1.y + b1};
    fvec2 r2 = {a2.x + b2, a2.y + b2};

    __builtin_nontemporal_store(r0, (fvec2*)(ob + 0 * (size_t)HW_));
    __builtin_nontemporal_store(r1, (fvec2*)(ob + 1 * (size_t)HW_));
    __builtin_nontemporal_store(r2, (fvec2*)(ob + 2 * (size_t)HW_));
}

extern "C" void kernel_launch(void* const* d_in, const int* in_sizes, int n_in,
                              void* d_out, int out_size, void* d_ws, size_t ws_size,
                              hipStream_t stream) {
    const float* x        = (const float*)d_in[0];  // (16,128,256,256)
    const float* w        = (const float*)d_in[1];  // (16,512)
    const float* weight   = (const float*)d_in[2];  // (3,128,1,1)
    const float* bias     = (const float*)d_in[3];  // (3,)
    const float* affine_b = (const float*)d_in[5];  // (128,)
    const float* affine_w = (const float*)d_in[4];  // (128,512)
    float* out = (float*)d_out;                     // (16,3,256,256)

    fvec4* coeff = (fvec4*)d_ws;                    // 16*128*16 B = 32 KB

    style_coeff_kernel<<<dim3(B_), dim3(CIN_), 0, stream>>>(
        w, weight, affine_w, affine_b, coeff);

    dim3 grid(HW_ / 512, B_);  // (128, 16) = 2048 blocks, 8/CU, 32 waves/CU
    torgb_kernel<<<grid, dim3(256), 0, stream>>>(x, coeff, bias, out);
}